// Round 6
// baseline (2703.552 us; speedup 1.0000x reference)
//
#include <hip/hip_runtime.h>
#include <hip/hip_fp16.h>

#define HDIM 64
#define HFC 32
#define NCLS 10
#define DTILE 16

__device__ inline __half2 u2h2(unsigned int u) {
    __half2 r;
    *reinterpret_cast<unsigned int*>(&r) = u;
    return r;
}
__device__ inline unsigned int h22u(__half2 h) {
    return *reinterpret_cast<unsigned int*>(&h);
}

// ================= CSR build =================

__global__ void k_count(const int* __restrict__ dst, int* __restrict__ degi, int E) {
    int e = blockIdx.x * blockDim.x + threadIdx.x;
    if (e < E) atomicAdd(&degi[dst[e]], 1);
}

__global__ void k_dinv2(const int* __restrict__ degi, float* __restrict__ dinv, int n) {
    int i = blockIdx.x * blockDim.x + threadIdx.x;
    if (i < n) dinv[i] = rsqrtf((float)degi[i] + 1.0f);   // +1 self-loop
}

__global__ void k_scan1(const int* __restrict__ degi, int* __restrict__ bsum, int n) {
    __shared__ int red[256];
    int base = blockIdx.x * 1024;
    int s = 0;
    for (int i = threadIdx.x; i < 1024; i += 256) {
        int idx = base + i;
        s += (idx < n) ? degi[idx] : 0;
    }
    red[threadIdx.x] = s; __syncthreads();
    for (int o = 128; o > 0; o >>= 1) {
        if (threadIdx.x < o) red[threadIdx.x] += red[threadIdx.x + o];
        __syncthreads();
    }
    if (threadIdx.x == 0) bsum[blockIdx.x] = red[0];
}

__global__ void k_scan2(int* __restrict__ bsum, int nb) {
    __shared__ int sh[1024];
    int v = (threadIdx.x < nb) ? bsum[threadIdx.x] : 0;
    sh[threadIdx.x] = v; __syncthreads();
    for (int o = 1; o < 1024; o <<= 1) {
        int t = (threadIdx.x >= (unsigned)o) ? sh[threadIdx.x - o] : 0;
        __syncthreads();
        sh[threadIdx.x] += t;
        __syncthreads();
    }
    if (threadIdx.x < nb) bsum[threadIdx.x] = sh[threadIdx.x] - v;  // exclusive
}

__global__ void k_scan3(const int* __restrict__ degi, const int* __restrict__ bsum,
                        int* __restrict__ rowptr, int n) {
    __shared__ int red[256];
    int bbase = bsum[blockIdx.x];
    int idx0 = blockIdx.x * 1024 + threadIdx.x * 4;
    int d0 = (idx0 + 0 < n) ? degi[idx0 + 0] : 0;
    int d1 = (idx0 + 1 < n) ? degi[idx0 + 1] : 0;
    int d2 = (idx0 + 2 < n) ? degi[idx0 + 2] : 0;
    int d3 = (idx0 + 3 < n) ? degi[idx0 + 3] : 0;
    int tsum = d0 + d1 + d2 + d3;
    red[threadIdx.x] = tsum; __syncthreads();
    for (int o = 1; o < 256; o <<= 1) {
        int t = (threadIdx.x >= (unsigned)o) ? red[threadIdx.x - o] : 0;
        __syncthreads();
        red[threadIdx.x] += t;
        __syncthreads();
    }
    int texcl = red[threadIdx.x] - tsum + bbase;
    if (idx0 + 0 < n) rowptr[idx0 + 1] = texcl + d0;
    if (idx0 + 1 < n) rowptr[idx0 + 2] = texcl + d0 + d1;
    if (idx0 + 2 < n) rowptr[idx0 + 3] = texcl + d0 + d1 + d2;
    if (idx0 + 3 < n) rowptr[idx0 + 4] = texcl + tsum;
    if (blockIdx.x == 0 && threadIdx.x == 0) rowptr[0] = 0;
}

__global__ void k_copycur(const int* __restrict__ rowptr, int* __restrict__ cursor, int n) {
    int i = blockIdx.x * blockDim.x + threadIdx.x;
    if (i < n) cursor[i] = rowptr[i];
}

__global__ void k_fill(const int* __restrict__ src, const int* __restrict__ dst,
                       int* __restrict__ cursor, int* __restrict__ col, int E) {
    int e = blockIdx.x * blockDim.x + threadIdx.x;
    if (e >= E) return;
    int p = atomicAdd(&cursor[dst[e]], 1);
    col[p] = src[e];
}

// ================= layer 1 =================

__global__ void k_xs(const float* __restrict__ x, const float* __restrict__ dinv,
                     float* __restrict__ xs, int n2) {
    int gid = blockIdx.x * blockDim.x + threadIdx.x;
    if (gid < n2) xs[gid] = x[gid] * dinv[gid >> 1];
}

__global__ void k_gather1(const int* __restrict__ rowptr, const int* __restrict__ col,
                          const float* __restrict__ xs, const float* __restrict__ dinv,
                          float* __restrict__ agg2, int n) {
    int d = blockIdx.x * blockDim.x + threadIdx.x;
    if (d >= n) return;
    const float2* xs2 = reinterpret_cast<const float2*>(xs);
    float2 v = xs2[d];
    float a0 = v.x, a1 = v.y;
    int e0 = rowptr[d], e1 = rowptr[d + 1];
    for (int e = e0; e < e1; ++e) {
        float2 w = xs2[col[e]];
        a0 += w.x; a1 += w.y;
    }
    float dv = dinv[d];
    agg2[2 * d] = a0 * dv;
    agg2[2 * d + 1] = a1 * dv;
}

// dense 2->64 with WIDE (uint2) fp16 stores; output scaled by dinv (next layer's gather src)
__global__ void k_dense2w(const float* __restrict__ agg2, const float* __restrict__ W,
                          const float* __restrict__ b, const float* __restrict__ dinv,
                          __half* __restrict__ out, int n) {
    int gid = blockIdx.x * blockDim.x + threadIdx.x;   // n*16
    if (gid >= n * 16) return;
    int node = gid >> 4;
    int q = gid & 15;
    float a0 = agg2[node * 2 + 0], a1 = agg2[node * 2 + 1];
    float dv = dinv[node];
    float r[4];
    #pragma unroll
    for (int j = 0; j < 4; ++j) {
        int f = q * 4 + j;
        float acc = fmaf(a0, W[f], fmaf(a1, W[HDIM + f], b[f]));
        r[j] = fmaxf(acc, 0.0f) * dv;
    }
    uint2 o;
    o.x = h22u(__floats2half2_rn(r[0], r[1]));
    o.y = h22u(__floats2half2_rn(r[2], r[3]));
    reinterpret_cast<uint2*>(out)[(long long)node * 16 + q] = o;
}

// ================= fused gather + dense (layers 2/3) =================
// block = 256 threads = 16 nodes x 16 quads
// phase 1: gather neighbors (uint2 loads) -> fp32 sAgg
// phase 2: 64x64 dense from LDS (conflict-free)
// phase 3: pack fp16 in LDS, wide uint2 global stores
__global__ void k_layer64(const int* __restrict__ rowptr, const int* __restrict__ col,
                          const __half* __restrict__ hs, const float* __restrict__ dinv,
                          const float* __restrict__ W, const float* __restrict__ b,
                          const float* __restrict__ dinv_out,   // nullptr => unscaled
                          __half* __restrict__ out, int n) {
    __shared__ float sW[HDIM * HDIM];
    __shared__ float sB[HDIM];
    __shared__ float sAgg[DTILE][HDIM];
    __shared__ __half sOut[DTILE][HDIM];

    for (int i = threadIdx.x; i < HDIM * HDIM; i += 256) sW[i] = W[i];
    if (threadIdx.x < HDIM) sB[threadIdx.x] = b[threadIdx.x];

    const int nd = threadIdx.x >> 4;          // node-in-tile
    const int q  = threadIdx.x & 15;          // quad
    const int node = blockIdx.x * DTILE + nd;

    float a0 = 0.0f, a1 = 0.0f, a2 = 0.0f, a3 = 0.0f;
    if (node < n) {
        const uint2* rows = reinterpret_cast<const uint2*>(hs);
        uint2 v = rows[(long long)node * 16 + q];   // self-loop term
        float2 f0 = __half22float2(u2h2(v.x));
        float2 f1 = __half22float2(u2h2(v.y));
        a0 = f0.x; a1 = f0.y; a2 = f1.x; a3 = f1.y;
        int e0 = rowptr[node], e1 = rowptr[node + 1];
        for (int e = e0; e < e1; ++e) {
            int s = col[e];
            uint2 w = rows[(long long)s * 16 + q];
            float2 g0 = __half22float2(u2h2(w.x));
            float2 g1 = __half22float2(u2h2(w.y));
            a0 += g0.x; a1 += g0.y; a2 += g1.x; a3 += g1.y;
        }
        float dv = dinv[node];
        a0 *= dv; a1 *= dv; a2 *= dv; a3 *= dv;
    }
    // float4 LDS write (b128, conflict-free pattern)
    reinterpret_cast<float4*>(&sAgg[0][0])[nd * 16 + q] = make_float4(a0, a1, a2, a3);
    __syncthreads();

    // dense: f = lane feature, 4 node-rows per thread
    {
        const int f  = threadIdx.x & 63;
        const int ng = threadIdx.x >> 6;
        #pragma unroll
        for (int ii = ng; ii < DTILE; ii += 4) {
            float acc = sB[f];
            #pragma unroll
            for (int k = 0; k < HDIM; ++k)
                acc = fmaf(sAgg[ii][k], sW[k * HDIM + f], acc);
            int onode = blockIdx.x * DTILE + ii;
            float sc = (dinv_out && onode < n) ? dinv_out[onode] : 1.0f;
            sOut[ii][f] = __float2half(fmaxf(acc, 0.0f) * sc);
        }
    }
    __syncthreads();

    if (node < n) {
        uint2 o = reinterpret_cast<const uint2*>(&sOut[0][0])[nd * 16 + q];
        reinterpret_cast<uint2*>(out)[(long long)node * 16 + q] = o;
    }
}

// ================= pooling (segmented, batch sorted) / BN / head =================

__global__ void k_start(const int* __restrict__ batch, int* __restrict__ startArr,
                        int n, int G) {
    int g = blockIdx.x * blockDim.x + threadIdx.x;
    if (g > G) return;
    int lo = 0, hi = n;
    while (lo < hi) {
        int mid = (lo + hi) >> 1;
        if (batch[mid] < g) lo = mid + 1; else hi = mid;
    }
    startArr[g] = lo;
}

__global__ void k_pool_seg(const __half* __restrict__ h, const int* __restrict__ startArr,
                           float* __restrict__ pooled, int G) {
    int g = blockIdx.x;
    int f = threadIdx.x;   // 64 threads
    int s = startArr[g], e = startArr[g + 1];
    float acc = 0.0f;
    for (int i = s; i < e; ++i) acc += __half2float(h[(long long)i * HDIM + f]);
    int c = e - s;
    pooled[(long long)g * HDIM + f] = acc / (float)(c > 0 ? c : 1);
}

__global__ void k_bnstats(const float* __restrict__ pooled,
                          const float* __restrict__ gamma, const float* __restrict__ beta,
                          float* __restrict__ scale, float* __restrict__ shift, int G) {
    int f = blockIdx.x;
    __shared__ float ss[256], ss2[256];
    float s = 0.0f, s2 = 0.0f;
    for (int g = threadIdx.x; g < G; g += blockDim.x) {
        float v = pooled[(long long)g * HDIM + f];
        s += v; s2 += v * v;
    }
    ss[threadIdx.x] = s; ss2[threadIdx.x] = s2;
    __syncthreads();
    for (int off = 128; off > 0; off >>= 1) {
        if (threadIdx.x < off) {
            ss[threadIdx.x]  += ss[threadIdx.x + off];
            ss2[threadIdx.x] += ss2[threadIdx.x + off];
        }
        __syncthreads();
    }
    if (threadIdx.x == 0) {
        float mean = ss[0] / (float)G;
        float var  = ss2[0] / (float)G - mean * mean;
        float rstd = rsqrtf(var + 1e-5f);
        float sc = gamma[f] * rstd;
        scale[f] = sc;
        shift[f] = beta[f] - mean * sc;
    }
}

__global__ void k_head(const float* __restrict__ pooled,
                       const float* __restrict__ scale, const float* __restrict__ shift,
                       const float* __restrict__ fcW1, const float* __restrict__ fcb1,
                       const float* __restrict__ fcW2, const float* __restrict__ fcb2,
                       float* __restrict__ out, int G) {
    __shared__ float sW1[HDIM * HFC];
    __shared__ float sW2[HFC * NCLS];
    __shared__ float sb1[HFC], sb2[NCLS], ssc[HDIM], ssh[HDIM];
    for (int i = threadIdx.x; i < HDIM * HFC; i += blockDim.x) sW1[i] = fcW1[i];
    for (int i = threadIdx.x; i < HFC * NCLS; i += blockDim.x) sW2[i] = fcW2[i];
    if (threadIdx.x < HFC)  sb1[threadIdx.x] = fcb1[threadIdx.x];
    if (threadIdx.x < NCLS) sb2[threadIdx.x] = fcb2[threadIdx.x];
    if (threadIdx.x < HDIM) { ssc[threadIdx.x] = scale[threadIdx.x]; ssh[threadIdx.x] = shift[threadIdx.x]; }
    __syncthreads();
    int g = blockIdx.x * blockDim.x + threadIdx.x;
    if (g >= G) return;
    float bn[HDIM];
    #pragma unroll
    for (int f = 0; f < HDIM; ++f)
        bn[f] = pooled[(long long)g * HDIM + f] * ssc[f] + ssh[f];
    float hfc[HFC];
    #pragma unroll
    for (int j = 0; j < HFC; ++j) {
        float a = sb1[j];
        #pragma unroll
        for (int f = 0; f < HDIM; ++f) a = fmaf(bn[f], sW1[f * HFC + j], a);
        hfc[j] = fmaxf(a, 0.0f);
    }
    float lg[NCLS];
    float mx = -1e30f;
    #pragma unroll
    for (int c = 0; c < NCLS; ++c) {
        float a = sb2[c];
        #pragma unroll
        for (int j = 0; j < HFC; ++j) a = fmaf(hfc[j], sW2[j * NCLS + c], a);
        lg[c] = a;
        mx = fmaxf(mx, a);
    }
    float se = 0.0f;
    #pragma unroll
    for (int c = 0; c < NCLS; ++c) se += expf(lg[c] - mx);
    float lse = mx + logf(se);
    #pragma unroll
    for (int c = 0; c < NCLS; ++c) out[(long long)g * NCLS + c] = lg[c] - lse;
}

// ================= launch =================

static inline char* bump(char*& p, size_t bytes) {
    char* r = p;
    p += (bytes + 255) & ~(size_t)255;
    return r;
}

extern "C" void kernel_launch(void* const* d_in, const int* in_sizes, int n_in,
                              void* d_out, int out_size, void* d_ws, size_t ws_size,
                              hipStream_t stream) {
    const float* x     = (const float*)d_in[0];
    const int*   ei    = (const int*)d_in[1];
    const int*   batch = (const int*)d_in[2];
    const float* W1    = (const float*)d_in[3];
    const float* b1    = (const float*)d_in[4];
    const float* W2    = (const float*)d_in[5];
    const float* b2    = (const float*)d_in[6];
    const float* W3    = (const float*)d_in[7];
    const float* b3    = (const float*)d_in[8];
    const float* gamma = (const float*)d_in[9];
    const float* beta  = (const float*)d_in[10];
    const float* fcW1  = (const float*)d_in[11];
    const float* fcb1  = (const float*)d_in[12];
    const float* fcW2  = (const float*)d_in[13];
    const float* fcb2  = (const float*)d_in[14];

    const long long n = in_sizes[2];
    const int ni = (int)n;
    const int E = in_sizes[1] / 2;
    const int G = out_size / NCLS;
    const int* src = ei;
    const int* dst = ei + E;
    const int B = 256;
    const int nb1024 = (ni + 1023) / 1024;

    char* p = (char*)d_ws;
    int*   degi   = (int*)bump(p, n * 4);           // reused as cursor
    int*   rowptr = (int*)bump(p, (n + 1) * 4);
    float* dinv   = (float*)bump(p, n * 4);
    float* xs     = (float*)bump(p, 2 * n * 4);
    float* agg2   = (float*)bump(p, 2 * n * 4);
    int*   bsum   = (int*)bump(p, 1024 * 4);
    int*   startA = (int*)bump(p, (size_t)(G + 1) * 4);
    float* pooled = (float*)bump(p, (size_t)G * HDIM * 4);
    float* scale  = (float*)bump(p, 2 * HDIM * 4);
    float* shift  = scale + HDIM;
    __half* hA    = (__half*)bump(p, (size_t)HDIM * n * 2);
    __half* hB    = (__half*)bump(p, (size_t)HDIM * n * 2);
    int*   col    = (int*)bump(p, (size_t)E * 4);

    (void)hipMemsetAsync(degi, 0, n * 4, stream);

    // CSR build
    k_count<<<(E + B - 1) / B, B, 0, stream>>>(dst, degi, E);
    k_dinv2<<<(ni + B - 1) / B, B, 0, stream>>>(degi, dinv, ni);
    k_scan1<<<nb1024, B, 0, stream>>>(degi, bsum, ni);
    k_scan2<<<1, 1024, 0, stream>>>(bsum, nb1024);
    k_scan3<<<nb1024, B, 0, stream>>>(degi, bsum, rowptr, ni);
    k_copycur<<<(ni + B - 1) / B, B, 0, stream>>>(rowptr, degi, ni);
    k_fill<<<(E + B - 1) / B, B, 0, stream>>>(src, dst, degi, col, E);

    // graph boundaries
    k_start<<<(G + 1 + B - 1) / B, B, 0, stream>>>(batch, startA, ni, G);

    // layer 1
    k_xs<<<(2 * ni + B - 1) / B, B, 0, stream>>>(x, dinv, xs, 2 * ni);
    k_gather1<<<(ni + B - 1) / B, B, 0, stream>>>(rowptr, col, xs, dinv, agg2, ni);
    k_dense2w<<<(int)((n * 16 + B - 1) / B), B, 0, stream>>>(agg2, W1, b1, dinv, hA, ni);

    // layers 2/3 fused (gather+dense), ping-pong hA -> hB -> hA
    const int nblk = (ni + DTILE - 1) / DTILE;
    k_layer64<<<nblk, B, 0, stream>>>(rowptr, col, hA, dinv, W2, b2, dinv, hB, ni);
    k_layer64<<<nblk, B, 0, stream>>>(rowptr, col, hB, dinv, W3, b3, nullptr, hA, ni);

    // pool + BN + head
    k_pool_seg<<<G, HDIM, 0, stream>>>(hA, startA, pooled, G);
    k_bnstats<<<HDIM, B, 0, stream>>>(pooled, gamma, beta, scale, shift, G);
    k_head<<<(G + B - 1) / B, B, 0, stream>>>(pooled, scale, shift,
                                              fcW1, fcb1, fcW2, fcb2, (float*)d_out, G);
}

// Round 7
// 1855.815 us; speedup vs baseline: 1.4568x; 1.4568x over previous
//
#include <hip/hip_runtime.h>
#include <hip/hip_fp16.h>

#define HDIM 64
#define HFC 32
#define NCLS 10
#define DT32 32

__device__ inline __half2 u2h2(unsigned int u) {
    __half2 r;
    *reinterpret_cast<unsigned int*>(&r) = u;
    return r;
}
__device__ inline unsigned int h22u(__half2 h) {
    return *reinterpret_cast<unsigned int*>(&h);
}
__device__ inline void acc8(const uint4 w, float* a) {
    float2 f;
    f = __half22float2(u2h2(w.x)); a[0] += f.x; a[1] += f.y;
    f = __half22float2(u2h2(w.y)); a[2] += f.x; a[3] += f.y;
    f = __half22float2(u2h2(w.z)); a[4] += f.x; a[5] += f.y;
    f = __half22float2(u2h2(w.w)); a[6] += f.x; a[7] += f.y;
}

// ================= CSR build =================

__global__ void k_count(const int* __restrict__ dst, int* __restrict__ degi, int E) {
    int e = blockIdx.x * blockDim.x + threadIdx.x;
    if (e < E) atomicAdd(&degi[dst[e]], 1);
}

__global__ void k_dinv2(const int* __restrict__ degi, float* __restrict__ dinv, int n) {
    int i = blockIdx.x * blockDim.x + threadIdx.x;
    if (i < n) dinv[i] = rsqrtf((float)degi[i] + 1.0f);   // +1 self-loop
}

__global__ void k_scan1(const int* __restrict__ degi, int* __restrict__ bsum, int n) {
    __shared__ int red[256];
    int base = blockIdx.x * 1024;
    int s = 0;
    for (int i = threadIdx.x; i < 1024; i += 256) {
        int idx = base + i;
        s += (idx < n) ? degi[idx] : 0;
    }
    red[threadIdx.x] = s; __syncthreads();
    for (int o = 128; o > 0; o >>= 1) {
        if (threadIdx.x < o) red[threadIdx.x] += red[threadIdx.x + o];
        __syncthreads();
    }
    if (threadIdx.x == 0) bsum[blockIdx.x] = red[0];
}

__global__ void k_scan2(int* __restrict__ bsum, int nb) {
    __shared__ int sh[1024];
    int v = (threadIdx.x < nb) ? bsum[threadIdx.x] : 0;
    sh[threadIdx.x] = v; __syncthreads();
    for (int o = 1; o < 1024; o <<= 1) {
        int t = (threadIdx.x >= (unsigned)o) ? sh[threadIdx.x - o] : 0;
        __syncthreads();
        sh[threadIdx.x] += t;
        __syncthreads();
    }
    if (threadIdx.x < nb) bsum[threadIdx.x] = sh[threadIdx.x] - v;  // exclusive
}

// writes rowptr AND cursor copy (saves a pass)
__global__ void k_scan3(const int* __restrict__ degi, const int* __restrict__ bsum,
                        int* __restrict__ rowptr, int* __restrict__ cursor, int n) {
    __shared__ int red[256];
    int bbase = bsum[blockIdx.x];
    int idx0 = blockIdx.x * 1024 + threadIdx.x * 4;
    int d0 = (idx0 + 0 < n) ? degi[idx0 + 0] : 0;
    int d1 = (idx0 + 1 < n) ? degi[idx0 + 1] : 0;
    int d2 = (idx0 + 2 < n) ? degi[idx0 + 2] : 0;
    int d3 = (idx0 + 3 < n) ? degi[idx0 + 3] : 0;
    int tsum = d0 + d1 + d2 + d3;
    red[threadIdx.x] = tsum; __syncthreads();
    for (int o = 1; o < 256; o <<= 1) {
        int t = (threadIdx.x >= (unsigned)o) ? red[threadIdx.x - o] : 0;
        __syncthreads();
        red[threadIdx.x] += t;
        __syncthreads();
    }
    int texcl = red[threadIdx.x] - tsum + bbase;
    if (idx0 + 0 < n) { rowptr[idx0 + 1] = texcl + d0; cursor[idx0 + 0] = texcl; }
    if (idx0 + 1 < n) { rowptr[idx0 + 2] = texcl + d0 + d1; cursor[idx0 + 1] = texcl + d0; }
    if (idx0 + 2 < n) { rowptr[idx0 + 3] = texcl + d0 + d1 + d2; cursor[idx0 + 2] = texcl + d0 + d1; }
    if (idx0 + 3 < n) { rowptr[idx0 + 4] = texcl + tsum; cursor[idx0 + 3] = texcl + d0 + d1 + d2; }
    if (blockIdx.x == 0 && threadIdx.x == 0) rowptr[0] = 0;
}

__global__ void k_fill(const int* __restrict__ src, const int* __restrict__ dst,
                       int* __restrict__ cursor, int* __restrict__ col, int E) {
    int e = blockIdx.x * blockDim.x + threadIdx.x;
    if (e >= E) return;
    int p = atomicAdd(&cursor[dst[e]], 1);
    col[p] = src[e];
}

// ================= layer 1 =================

__global__ void k_xs(const float* __restrict__ x, const float* __restrict__ dinv,
                     float* __restrict__ xs, int n2) {
    int gid = blockIdx.x * blockDim.x + threadIdx.x;
    if (gid < n2) xs[gid] = x[gid] * dinv[gid >> 1];
}

__global__ void k_gather1(const int* __restrict__ rowptr, const int* __restrict__ col,
                          const float* __restrict__ xs, const float* __restrict__ dinv,
                          float* __restrict__ agg2, int n) {
    int d = blockIdx.x * blockDim.x + threadIdx.x;
    if (d >= n) return;
    const float2* xs2 = reinterpret_cast<const float2*>(xs);
    float2 v = xs2[d];
    float a0 = v.x, a1 = v.y;
    int e0 = rowptr[d], e1 = rowptr[d + 1];
    for (int e = e0; e < e1; ++e) {
        float2 w = xs2[col[e]];
        a0 += w.x; a1 += w.y;
    }
    float dv = dinv[d];
    agg2[2 * d] = a0 * dv;
    agg2[2 * d + 1] = a1 * dv;
}

// dense 2->64, 8 features/thread, dwordx4 stores; output scaled by dinv
__global__ void k_dense2w(const float* __restrict__ agg2, const float* __restrict__ W,
                          const float* __restrict__ b, const float* __restrict__ dinv,
                          __half* __restrict__ out, int n) {
    int gid = blockIdx.x * blockDim.x + threadIdx.x;   // n*8
    if (gid >= n * 8) return;
    int node = gid >> 3;
    int q = gid & 7;
    float a0 = agg2[node * 2 + 0], a1 = agg2[node * 2 + 1];
    float dv = dinv[node];
    float r[8];
    #pragma unroll
    for (int j = 0; j < 8; ++j) {
        int f = q * 8 + j;
        float acc = fmaf(a0, W[f], fmaf(a1, W[HDIM + f], b[f]));
        r[j] = fmaxf(acc, 0.0f) * dv;
    }
    uint4 o;
    o.x = h22u(__floats2half2_rn(r[0], r[1]));
    o.y = h22u(__floats2half2_rn(r[2], r[3]));
    o.z = h22u(__floats2half2_rn(r[4], r[5]));
    o.w = h22u(__floats2half2_rn(r[6], r[7]));
    reinterpret_cast<uint4*>(out)[(long long)node * 8 + q] = o;
}

// ================= fused gather + dense (layers 2/3) =================
// 256 thr = 32 nodes x 8 octs; uint4 (16B/lane) gathers and stores
__global__ __launch_bounds__(256) void k_layer64(
        const int* __restrict__ rowptr, const int* __restrict__ col,
        const __half* __restrict__ hs, const float* __restrict__ dinv,
        const float* __restrict__ W, const float* __restrict__ b,
        const float* __restrict__ dinv_out,   // nullptr => unscaled
        __half* __restrict__ out, int n) {
    __shared__ float sW[HDIM * HDIM];
    __shared__ float sB[HDIM];
    __shared__ float sAgg[DT32][HDIM];
    __shared__ __half sOut[DT32][HDIM];

    for (int i = threadIdx.x; i < HDIM * HDIM; i += 256) sW[i] = W[i];
    if (threadIdx.x < HDIM) sB[threadIdx.x] = b[threadIdx.x];

    const int nd = threadIdx.x >> 3;          // node-in-tile 0..31
    const int q  = threadIdx.x & 7;           // oct 0..7
    const int node = blockIdx.x * DT32 + nd;

    float a[8] = {0.f, 0.f, 0.f, 0.f, 0.f, 0.f, 0.f, 0.f};
    if (node < n) {
        const uint4* rows = reinterpret_cast<const uint4*>(hs);  // 8 uint4 / node row
        acc8(rows[(long long)node * 8 + q], a);                  // self-loop
        int e0 = rowptr[node], e1 = rowptr[node + 1];
        for (int e = e0; e < e1; ++e) {
            int s = col[e];
            acc8(rows[(long long)s * 8 + q], a);
        }
        float dv = dinv[node];
        #pragma unroll
        for (int j = 0; j < 8; ++j) a[j] *= dv;
    }
    float4* sa = reinterpret_cast<float4*>(&sAgg[nd][q * 8]);
    sa[0] = make_float4(a[0], a[1], a[2], a[3]);
    sa[1] = make_float4(a[4], a[5], a[6], a[7]);
    __syncthreads();

    // dense: f = lane feature, 8 node-rows per thread
    {
        const int f  = threadIdx.x & 63;
        const int ng = threadIdx.x >> 6;
        for (int ii = ng; ii < DT32; ii += 4) {
            float acc = sB[f];
            #pragma unroll
            for (int k = 0; k < HDIM; ++k)
                acc = fmaf(sAgg[ii][k], sW[k * HDIM + f], acc);
            int onode = blockIdx.x * DT32 + ii;
            float sc = 1.0f;
            if (dinv_out && onode < n) sc = dinv_out[onode];
            sOut[ii][f] = __float2half(fmaxf(acc, 0.0f) * sc);
        }
    }
    __syncthreads();

    if (node < n) {
        uint4 o = reinterpret_cast<const uint4*>(&sOut[0][0])[nd * 8 + q];
        reinterpret_cast<uint4*>(out)[(long long)node * 8 + q] = o;
    }
}

// ================= pooling / BN / head =================

__global__ void k_start(const int* __restrict__ batch, int* __restrict__ startArr,
                        int n, int G) {
    int g = blockIdx.x * blockDim.x + threadIdx.x;
    if (g > G) return;
    int lo = 0, hi = n;
    while (lo < hi) {
        int mid = (lo + hi) >> 1;
        if (batch[mid] < g) lo = mid + 1; else hi = mid;
    }
    startArr[g] = lo;
}

__global__ void k_pool_seg(const __half* __restrict__ h, const int* __restrict__ startArr,
                           float* __restrict__ pooled, int G) {
    int g = blockIdx.x;
    int f = threadIdx.x;   // 64 threads
    int s = startArr[g], e = startArr[g + 1];
    float acc = 0.0f;
    for (int i = s; i < e; ++i) acc += __half2float(h[(long long)i * HDIM + f]);
    int c = e - s;
    pooled[(long long)g * HDIM + f] = acc / (float)(c > 0 ? c : 1);
}

__global__ void k_bnstats(const float* __restrict__ pooled,
                          const float* __restrict__ gamma, const float* __restrict__ beta,
                          float* __restrict__ scale, float* __restrict__ shift, int G) {
    int f = blockIdx.x;
    __shared__ float ss[256], ss2[256];
    float s = 0.0f, s2 = 0.0f;
    for (int g = threadIdx.x; g < G; g += blockDim.x) {
        float v = pooled[(long long)g * HDIM + f];
        s += v; s2 += v * v;
    }
    ss[threadIdx.x] = s; ss2[threadIdx.x] = s2;
    __syncthreads();
    for (int off = 128; off > 0; off >>= 1) {
        if (threadIdx.x < off) {
            ss[threadIdx.x]  += ss[threadIdx.x + off];
            ss2[threadIdx.x] += ss2[threadIdx.x + off];
        }
        __syncthreads();
    }
    if (threadIdx.x == 0) {
        float mean = ss[0] / (float)G;
        float var  = ss2[0] / (float)G - mean * mean;
        float rstd = rsqrtf(var + 1e-5f);
        float sc = gamma[f] * rstd;
        scale[f] = sc;
        shift[f] = beta[f] - mean * sc;
    }
}

__global__ void k_head(const float* __restrict__ pooled,
                       const float* __restrict__ scale, const float* __restrict__ shift,
                       const float* __restrict__ fcW1, const float* __restrict__ fcb1,
                       const float* __restrict__ fcW2, const float* __restrict__ fcb2,
                       float* __restrict__ out, int G) {
    __shared__ float sW1[HDIM * HFC];
    __shared__ float sW2[HFC * NCLS];
    __shared__ float sb1[HFC], sb2[NCLS], ssc[HDIM], ssh[HDIM];
    for (int i = threadIdx.x; i < HDIM * HFC; i += blockDim.x) sW1[i] = fcW1[i];
    for (int i = threadIdx.x; i < HFC * NCLS; i += blockDim.x) sW2[i] = fcW2[i];
    if (threadIdx.x < HFC)  sb1[threadIdx.x] = fcb1[threadIdx.x];
    if (threadIdx.x < NCLS) sb2[threadIdx.x] = fcb2[threadIdx.x];
    if (threadIdx.x < HDIM) { ssc[threadIdx.x] = scale[threadIdx.x]; ssh[threadIdx.x] = shift[threadIdx.x]; }
    __syncthreads();
    int g = blockIdx.x * blockDim.x + threadIdx.x;
    if (g >= G) return;
    float bn[HDIM];
    #pragma unroll
    for (int f = 0; f < HDIM; ++f)
        bn[f] = pooled[(long long)g * HDIM + f] * ssc[f] + ssh[f];
    float hfc[HFC];
    #pragma unroll
    for (int j = 0; j < HFC; ++j) {
        float a = sb1[j];
        #pragma unroll
        for (int f = 0; f < HDIM; ++f) a = fmaf(bn[f], sW1[f * HFC + j], a);
        hfc[j] = fmaxf(a, 0.0f);
    }
    float lg[NCLS];
    float mx = -1e30f;
    #pragma unroll
    for (int c = 0; c < NCLS; ++c) {
        float a = sb2[c];
        #pragma unroll
        for (int j = 0; j < HFC; ++j) a = fmaf(hfc[j], sW2[j * NCLS + c], a);
        lg[c] = a;
        mx = fmaxf(mx, a);
    }
    float se = 0.0f;
    #pragma unroll
    for (int c = 0; c < NCLS; ++c) se += expf(lg[c] - mx);
    float lse = mx + logf(se);
    #pragma unroll
    for (int c = 0; c < NCLS; ++c) out[(long long)g * NCLS + c] = lg[c] - lse;
}

// ================= launch =================

static inline char* bump(char*& p, size_t bytes) {
    char* r = p;
    p += (bytes + 255) & ~(size_t)255;
    return r;
}

extern "C" void kernel_launch(void* const* d_in, const int* in_sizes, int n_in,
                              void* d_out, int out_size, void* d_ws, size_t ws_size,
                              hipStream_t stream) {
    const float* x     = (const float*)d_in[0];
    const int*   ei    = (const int*)d_in[1];
    const int*   batch = (const int*)d_in[2];
    const float* W1    = (const float*)d_in[3];
    const float* b1    = (const float*)d_in[4];
    const float* W2    = (const float*)d_in[5];
    const float* b2    = (const float*)d_in[6];
    const float* W3    = (const float*)d_in[7];
    const float* b3    = (const float*)d_in[8];
    const float* gamma = (const float*)d_in[9];
    const float* beta  = (const float*)d_in[10];
    const float* fcW1  = (const float*)d_in[11];
    const float* fcb1  = (const float*)d_in[12];
    const float* fcW2  = (const float*)d_in[13];
    const float* fcb2  = (const float*)d_in[14];

    const long long n = in_sizes[2];
    const int ni = (int)n;
    const int E = in_sizes[1] / 2;
    const int G = out_size / NCLS;
    const int* src = ei;
    const int* dst = ei + E;
    const int B = 256;
    const int nb1024 = (ni + 1023) / 1024;

    char* p = (char*)d_ws;
    int*   degi   = (int*)bump(p, n * 4);
    int*   cursor = (int*)bump(p, n * 4);
    int*   rowptr = (int*)bump(p, (n + 1) * 4);
    float* dinv   = (float*)bump(p, n * 4);
    float* xs     = (float*)bump(p, 2 * n * 4);
    float* agg2   = (float*)bump(p, 2 * n * 4);
    int*   bsum   = (int*)bump(p, 1024 * 4);
    int*   startA = (int*)bump(p, (size_t)(G + 1) * 4);
    float* pooled = (float*)bump(p, (size_t)G * HDIM * 4);
    float* scale  = (float*)bump(p, 2 * HDIM * 4);
    float* shift  = scale + HDIM;
    __half* hA    = (__half*)bump(p, (size_t)HDIM * n * 2);
    __half* hB    = (__half*)bump(p, (size_t)HDIM * n * 2);
    int*   col    = (int*)bump(p, (size_t)E * 4);

    (void)hipMemsetAsync(degi, 0, n * 4, stream);

    // CSR build
    k_count<<<(E + B - 1) / B, B, 0, stream>>>(dst, degi, E);
    k_dinv2<<<(ni + B - 1) / B, B, 0, stream>>>(degi, dinv, ni);
    k_scan1<<<nb1024, B, 0, stream>>>(degi, bsum, ni);
    k_scan2<<<1, 1024, 0, stream>>>(bsum, nb1024);
    k_scan3<<<nb1024, B, 0, stream>>>(degi, bsum, rowptr, cursor, ni);
    k_fill<<<(E + B - 1) / B, B, 0, stream>>>(src, dst, cursor, col, E);

    // graph boundaries
    k_start<<<(G + 1 + B - 1) / B, B, 0, stream>>>(batch, startA, ni, G);

    // layer 1
    k_xs<<<(2 * ni + B - 1) / B, B, 0, stream>>>(x, dinv, xs, 2 * ni);
    k_gather1<<<(ni + B - 1) / B, B, 0, stream>>>(rowptr, col, xs, dinv, agg2, ni);
    k_dense2w<<<(int)((n * 8 + B - 1) / B), B, 0, stream>>>(agg2, W1, b1, dinv, hA, ni);

    // layers 2/3 fused, ping-pong hA -> hB -> hA
    const int nblk = (ni + DT32 - 1) / DT32;
    k_layer64<<<nblk, B, 0, stream>>>(rowptr, col, hA, dinv, W2, b2, dinv, hB, ni);
    k_layer64<<<nblk, B, 0, stream>>>(rowptr, col, hB, dinv, W3, b3, nullptr, hA, ni);

    // pool + BN + head
    k_pool_seg<<<G, HDIM, 0, stream>>>(hA, startA, pooled, G);
    k_bnstats<<<HDIM, B, 0, stream>>>(pooled, gamma, beta, scale, shift, G);
    k_head<<<(G + B - 1) / B, B, 0, stream>>>(pooled, scale, shift,
                                              fcW1, fcb1, fcW2, fcb2, (float*)d_out, G);
}

// Round 8
// 1350.307 us; speedup vs baseline: 2.0022x; 1.3744x over previous
//
#include <hip/hip_runtime.h>
#include <hip/hip_fp16.h>

#define HDIM 64
#define HFC 32
#define NCLS 10
#define DT32 32

// CSR-build bucketing
#define NBUCK 256      // max buckets (supports n <= 1M)
#define BSH   12       // 4096 nodes per bucket
#define BUCKN 4096
#define EPT   16       // edges per thread in hist/split
#define CHUNK 4096     // edges per block (256 thr * 16)

__device__ inline __half2 u2h2(unsigned int u) {
    __half2 r;
    *reinterpret_cast<unsigned int*>(&r) = u;
    return r;
}
__device__ inline unsigned int h22u(__half2 h) {
    return *reinterpret_cast<unsigned int*>(&h);
}
__device__ inline void acc8(const uint4 w, float* a) {
    float2 f;
    f = __half22float2(u2h2(w.x)); a[0] += f.x; a[1] += f.y;
    f = __half22float2(u2h2(w.y)); a[2] += f.x; a[3] += f.y;
    f = __half22float2(u2h2(w.z)); a[4] += f.x; a[5] += f.y;
    f = __half22float2(u2h2(w.w)); a[6] += f.x; a[7] += f.y;
}

// ================= CSR build: hist -> scan -> split -> build =================

__global__ __launch_bounds__(256) void k_hist(const int* __restrict__ dst,
                                              int* __restrict__ ghist, int E) {
    __shared__ int h[NBUCK];
    h[threadIdx.x] = 0;
    __syncthreads();
    int base = blockIdx.x * CHUNK + threadIdx.x;
    #pragma unroll
    for (int i = 0; i < EPT; ++i) {
        int e = base + i * 256;
        if (e < E) atomicAdd(&h[dst[e] >> BSH], 1);
    }
    __syncthreads();
    if (h[threadIdx.x]) atomicAdd(&ghist[threadIdx.x], h[threadIdx.x]);
}

// single block, 256 threads: exclusive scan of ghist -> bucketBase, gcur
__global__ void k_bscan(const int* __restrict__ ghist, int* __restrict__ bucketBase,
                        int* __restrict__ gcur, int* __restrict__ rowptr, int n, int E) {
    __shared__ int sh[NBUCK];
    int v = ghist[threadIdx.x];
    sh[threadIdx.x] = v; __syncthreads();
    for (int o = 1; o < NBUCK; o <<= 1) {
        int t = ((int)threadIdx.x >= o) ? sh[threadIdx.x - o] : 0;
        __syncthreads();
        sh[threadIdx.x] += t;
        __syncthreads();
    }
    int excl = sh[threadIdx.x] - v;
    bucketBase[threadIdx.x] = excl;
    gcur[threadIdx.x] = excl;
    if (threadIdx.x == NBUCK - 1) { bucketBase[NBUCK] = E; rowptr[n] = E; }
}

// bin edges into bucket-grouped partition array (packed u64: dst<<32 | src)
__global__ __launch_bounds__(256) void k_split(const int* __restrict__ src,
                                               const int* __restrict__ dst,
                                               int* __restrict__ gcur,
                                               unsigned long long* __restrict__ part, int E) {
    __shared__ int cnt[NBUCK];
    __shared__ int off[NBUCK];
    cnt[threadIdx.x] = 0;
    __syncthreads();
    int base = blockIdx.x * CHUNK + threadIdx.x;
    int s16[EPT], d16[EPT], b16[EPT];
    #pragma unroll
    for (int i = 0; i < EPT; ++i) {
        int e = base + i * 256;
        bool ok = e < E;
        s16[i] = ok ? src[e] : 0;
        d16[i] = ok ? dst[e] : 0;
        b16[i] = ok ? (d16[i] >> BSH) : -1;
        if (ok) atomicAdd(&cnt[b16[i]], 1);
    }
    __syncthreads();
    {
        int c = cnt[threadIdx.x];
        off[threadIdx.x] = c ? atomicAdd(&gcur[threadIdx.x], c) : 0;
    }
    __syncthreads();
    #pragma unroll
    for (int i = 0; i < EPT; ++i) {
        if (b16[i] >= 0) {
            int slot = atomicAdd(&off[b16[i]], 1);
            part[slot] = ((unsigned long long)(unsigned)d16[i] << 32) | (unsigned)s16[i];
        }
    }
}

// one block per bucket: count per-node in LDS, scan, emit rowptr+dinv, fill col
__global__ __launch_bounds__(256) void k_build(const unsigned long long* __restrict__ part,
                                               const int* __restrict__ bucketBase,
                                               int* __restrict__ rowptr,
                                               float* __restrict__ dinv,
                                               int* __restrict__ col, int n) {
    __shared__ int cnt[BUCKN];
    __shared__ int tmp[256];
    const int b = blockIdx.x;
    const int s = bucketBase[b], t = bucketBase[b + 1];
    const int nodeBase = b << BSH;
    for (int i = threadIdx.x; i < BUCKN; i += 256) cnt[i] = 0;
    __syncthreads();
    for (int e = s + threadIdx.x; e < t; e += 256) {
        unsigned long long pe = part[e];
        int local = (int)(pe >> 32) & (BUCKN - 1);
        atomicAdd(&cnt[local], 1);
    }
    __syncthreads();
    // block scan: each thread owns 16 consecutive counters
    int my[16]; int sum = 0;
    #pragma unroll
    for (int i = 0; i < 16; ++i) { my[i] = cnt[threadIdx.x * 16 + i]; sum += my[i]; }
    tmp[threadIdx.x] = sum; __syncthreads();
    for (int o = 1; o < 256; o <<= 1) {
        int v = ((int)threadIdx.x >= o) ? tmp[threadIdx.x - o] : 0;
        __syncthreads();
        tmp[threadIdx.x] += v;
        __syncthreads();
    }
    int run = tmp[threadIdx.x] - sum + s;   // global col base for first owned node
    __syncthreads();   // all reads of cnt done before overwrite
    #pragma unroll
    for (int i = 0; i < 16; ++i) {
        int local = threadIdx.x * 16 + i;
        int node = nodeBase + local;
        int c = my[i];
        cnt[local] = run;   // reuse cnt as global-position cursor
        if (node < n) { rowptr[node] = run; dinv[node] = rsqrtf((float)c + 1.0f); }
        run += c;
    }
    __syncthreads();
    for (int e = s + threadIdx.x; e < t; e += 256) {
        unsigned long long pe = part[e];
        int local = (int)(pe >> 32) & (BUCKN - 1);
        int p = atomicAdd(&cnt[local], 1);
        col[p] = (int)(pe & 0xffffffffu);
    }
}

// ================= layer 1 =================

__global__ void k_xs(const float* __restrict__ x, const float* __restrict__ dinv,
                     float* __restrict__ xs, int n2) {
    int gid = blockIdx.x * blockDim.x + threadIdx.x;
    if (gid < n2) xs[gid] = x[gid] * dinv[gid >> 1];
}

__global__ void k_gather1(const int* __restrict__ rowptr, const int* __restrict__ col,
                          const float* __restrict__ xs, const float* __restrict__ dinv,
                          float* __restrict__ agg2, int n) {
    int d = blockIdx.x * blockDim.x + threadIdx.x;
    if (d >= n) return;
    const float2* xs2 = reinterpret_cast<const float2*>(xs);
    float2 v = xs2[d];
    float a0 = v.x, a1 = v.y;
    int e0 = rowptr[d], e1 = rowptr[d + 1];
    for (int e = e0; e < e1; ++e) {
        float2 w = xs2[col[e]];
        a0 += w.x; a1 += w.y;
    }
    float dv = dinv[d];
    agg2[2 * d] = a0 * dv;
    agg2[2 * d + 1] = a1 * dv;
}

// dense 2->64, 8 features/thread, dwordx4 stores; output scaled by dinv
__global__ void k_dense2w(const float* __restrict__ agg2, const float* __restrict__ W,
                          const float* __restrict__ b, const float* __restrict__ dinv,
                          __half* __restrict__ out, int n) {
    int gid = blockIdx.x * blockDim.x + threadIdx.x;   // n*8
    if (gid >= n * 8) return;
    int node = gid >> 3;
    int q = gid & 7;
    float a0 = agg2[node * 2 + 0], a1 = agg2[node * 2 + 1];
    float dv = dinv[node];
    float r[8];
    #pragma unroll
    for (int j = 0; j < 8; ++j) {
        int f = q * 8 + j;
        float acc = fmaf(a0, W[f], fmaf(a1, W[HDIM + f], b[f]));
        r[j] = fmaxf(acc, 0.0f) * dv;
    }
    uint4 o;
    o.x = h22u(__floats2half2_rn(r[0], r[1]));
    o.y = h22u(__floats2half2_rn(r[2], r[3]));
    o.z = h22u(__floats2half2_rn(r[4], r[5]));
    o.w = h22u(__floats2half2_rn(r[6], r[7]));
    reinterpret_cast<uint4*>(out)[(long long)node * 8 + q] = o;
}

// ================= fused gather + dense (layers 2/3) =================
__global__ __launch_bounds__(256) void k_layer64(
        const int* __restrict__ rowptr, const int* __restrict__ col,
        const __half* __restrict__ hs, const float* __restrict__ dinv,
        const float* __restrict__ W, const float* __restrict__ b,
        const float* __restrict__ dinv_out,   // nullptr => unscaled
        __half* __restrict__ out, int n) {
    __shared__ float sW[HDIM * HDIM];
    __shared__ float sB[HDIM];
    __shared__ float sAgg[DT32][HDIM];
    __shared__ __half sOut[DT32][HDIM];

    for (int i = threadIdx.x; i < HDIM * HDIM; i += 256) sW[i] = W[i];
    if (threadIdx.x < HDIM) sB[threadIdx.x] = b[threadIdx.x];

    const int nd = threadIdx.x >> 3;          // node-in-tile 0..31
    const int q  = threadIdx.x & 7;           // oct 0..7
    const int node = blockIdx.x * DT32 + nd;

    float a[8] = {0.f, 0.f, 0.f, 0.f, 0.f, 0.f, 0.f, 0.f};
    if (node < n) {
        const uint4* rows = reinterpret_cast<const uint4*>(hs);
        acc8(rows[(long long)node * 8 + q], a);
        int e0 = rowptr[node], e1 = rowptr[node + 1];
        for (int e = e0; e < e1; ++e) {
            int s = col[e];
            acc8(rows[(long long)s * 8 + q], a);
        }
        float dv = dinv[node];
        #pragma unroll
        for (int j = 0; j < 8; ++j) a[j] *= dv;
    }
    float4* sa = reinterpret_cast<float4*>(&sAgg[nd][q * 8]);
    sa[0] = make_float4(a[0], a[1], a[2], a[3]);
    sa[1] = make_float4(a[4], a[5], a[6], a[7]);
    __syncthreads();

    {
        const int f  = threadIdx.x & 63;
        const int ng = threadIdx.x >> 6;
        for (int ii = ng; ii < DT32; ii += 4) {
            float acc = sB[f];
            #pragma unroll
            for (int k = 0; k < HDIM; ++k)
                acc = fmaf(sAgg[ii][k], sW[k * HDIM + f], acc);
            int onode = blockIdx.x * DT32 + ii;
            float sc = 1.0f;
            if (dinv_out && onode < n) sc = dinv_out[onode];
            sOut[ii][f] = __float2half(fmaxf(acc, 0.0f) * sc);
        }
    }
    __syncthreads();

    if (node < n) {
        uint4 o = reinterpret_cast<const uint4*>(&sOut[0][0])[nd * 8 + q];
        reinterpret_cast<uint4*>(out)[(long long)node * 8 + q] = o;
    }
}

// ================= pooling / BN / head =================

__global__ void k_start(const int* __restrict__ batch, int* __restrict__ startArr,
                        int n, int G) {
    int g = blockIdx.x * blockDim.x + threadIdx.x;
    if (g > G) return;
    int lo = 0, hi = n;
    while (lo < hi) {
        int mid = (lo + hi) >> 1;
        if (batch[mid] < g) lo = mid + 1; else hi = mid;
    }
    startArr[g] = lo;
}

// 4 graphs per 256-thread block
__global__ void k_pool_seg(const __half* __restrict__ h, const int* __restrict__ startArr,
                           float* __restrict__ pooled, int G) {
    int g = blockIdx.x * 4 + (threadIdx.x >> 6);
    int f = threadIdx.x & 63;
    if (g >= G) return;
    int s = startArr[g], e = startArr[g + 1];
    float acc = 0.0f;
    for (int i = s; i < e; ++i) acc += __half2float(h[(long long)i * HDIM + f]);
    int c = e - s;
    pooled[(long long)g * HDIM + f] = acc / (float)(c > 0 ? c : 1);
}

__global__ void k_bnstats(const float* __restrict__ pooled,
                          const float* __restrict__ gamma, const float* __restrict__ beta,
                          float* __restrict__ scale, float* __restrict__ shift, int G) {
    int f = blockIdx.x;
    __shared__ float ss[256], ss2[256];
    float s = 0.0f, s2 = 0.0f;
    for (int g = threadIdx.x; g < G; g += blockDim.x) {
        float v = pooled[(long long)g * HDIM + f];
        s += v; s2 += v * v;
    }
    ss[threadIdx.x] = s; ss2[threadIdx.x] = s2;
    __syncthreads();
    for (int off = 128; off > 0; off >>= 1) {
        if (threadIdx.x < off) {
            ss[threadIdx.x]  += ss[threadIdx.x + off];
            ss2[threadIdx.x] += ss2[threadIdx.x + off];
        }
        __syncthreads();
    }
    if (threadIdx.x == 0) {
        float mean = ss[0] / (float)G;
        float var  = ss2[0] / (float)G - mean * mean;
        float rstd = rsqrtf(var + 1e-5f);
        float sc = gamma[f] * rstd;
        scale[f] = sc;
        shift[f] = beta[f] - mean * sc;
    }
}

__global__ void k_head(const float* __restrict__ pooled,
                       const float* __restrict__ scale, const float* __restrict__ shift,
                       const float* __restrict__ fcW1, const float* __restrict__ fcb1,
                       const float* __restrict__ fcW2, const float* __restrict__ fcb2,
                       float* __restrict__ out, int G) {
    __shared__ float sW1[HDIM * HFC];
    __shared__ float sW2[HFC * NCLS];
    __shared__ float sb1[HFC], sb2[NCLS], ssc[HDIM], ssh[HDIM];
    for (int i = threadIdx.x; i < HDIM * HFC; i += blockDim.x) sW1[i] = fcW1[i];
    for (int i = threadIdx.x; i < HFC * NCLS; i += blockDim.x) sW2[i] = fcW2[i];
    if (threadIdx.x < HFC)  sb1[threadIdx.x] = fcb1[threadIdx.x];
    if (threadIdx.x < NCLS) sb2[threadIdx.x] = fcb2[threadIdx.x];
    if (threadIdx.x < HDIM) { ssc[threadIdx.x] = scale[threadIdx.x]; ssh[threadIdx.x] = shift[threadIdx.x]; }
    __syncthreads();
    int g = blockIdx.x * blockDim.x + threadIdx.x;
    if (g >= G) return;
    float bn[HDIM];
    #pragma unroll
    for (int f = 0; f < HDIM; ++f)
        bn[f] = pooled[(long long)g * HDIM + f] * ssc[f] + ssh[f];
    float hfc[HFC];
    #pragma unroll
    for (int j = 0; j < HFC; ++j) {
        float a = sb1[j];
        #pragma unroll
        for (int f = 0; f < HDIM; ++f) a = fmaf(bn[f], sW1[f * HFC + j], a);
        hfc[j] = fmaxf(a, 0.0f);
    }
    float lg[NCLS];
    float mx = -1e30f;
    #pragma unroll
    for (int c = 0; c < NCLS; ++c) {
        float a = sb2[c];
        #pragma unroll
        for (int j = 0; j < HFC; ++j) a = fmaf(hfc[j], sW2[j * NCLS + c], a);
        lg[c] = a;
        mx = fmaxf(mx, a);
    }
    float se = 0.0f;
    #pragma unroll
    for (int c = 0; c < NCLS; ++c) se += expf(lg[c] - mx);
    float lse = mx + logf(se);
    #pragma unroll
    for (int c = 0; c < NCLS; ++c) out[(long long)g * NCLS + c] = lg[c] - lse;
}

// ================= launch =================

static inline char* bump(char*& p, size_t bytes) {
    char* r = p;
    p += (bytes + 255) & ~(size_t)255;
    return r;
}

extern "C" void kernel_launch(void* const* d_in, const int* in_sizes, int n_in,
                              void* d_out, int out_size, void* d_ws, size_t ws_size,
                              hipStream_t stream) {
    const float* x     = (const float*)d_in[0];
    const int*   ei    = (const int*)d_in[1];
    const int*   batch = (const int*)d_in[2];
    const float* W1    = (const float*)d_in[3];
    const float* b1    = (const float*)d_in[4];
    const float* W2    = (const float*)d_in[5];
    const float* b2    = (const float*)d_in[6];
    const float* W3    = (const float*)d_in[7];
    const float* b3    = (const float*)d_in[8];
    const float* gamma = (const float*)d_in[9];
    const float* beta  = (const float*)d_in[10];
    const float* fcW1  = (const float*)d_in[11];
    const float* fcb1  = (const float*)d_in[12];
    const float* fcW2  = (const float*)d_in[13];
    const float* fcb2  = (const float*)d_in[14];

    const long long n = in_sizes[2];
    const int ni = (int)n;
    const int E = in_sizes[1] / 2;
    const int G = out_size / NCLS;
    const int* src = ei;
    const int* dst = ei + E;
    const int B = 256;

    char* p = (char*)d_ws;
    int*   ghist  = (int*)bump(p, NBUCK * 4);
    int*   bktB   = (int*)bump(p, (NBUCK + 1) * 4);
    int*   gcur   = (int*)bump(p, NBUCK * 4);
    int*   rowptr = (int*)bump(p, (n + 1) * 4);
    float* dinv   = (float*)bump(p, n * 4);
    int*   startA = (int*)bump(p, (size_t)(G + 1) * 4);
    float* pooled = (float*)bump(p, (size_t)G * HDIM * 4);
    float* scale  = (float*)bump(p, 2 * HDIM * 4);
    float* shift  = scale + HDIM;
    __half* hA    = (__half*)bump(p, (size_t)HDIM * n * 2);
    char*  R      = bump(p, (size_t)HDIM * n * 2);     // 96MB region, multi-use
    int*   col    = (int*)bump(p, (size_t)E * 4);

    // aliases inside R: part (48MB) + xs (6MB) + agg2 (6MB) live before hB
    unsigned long long* part = (unsigned long long*)R;
    float* xs   = (float*)(R + (((size_t)E * 8 + 255) & ~(size_t)255));
    float* agg2 = xs + 2 * n;
    __half* hB  = (__half*)R;

    (void)hipMemsetAsync(ghist, 0, NBUCK * 4, stream);

    // CSR build (bucketed counting sort)
    const int nchunk = (E + CHUNK - 1) / CHUNK;
    const int nbU = (ni + BUCKN - 1) >> BSH;
    k_hist<<<nchunk, B, 0, stream>>>(dst, ghist, E);
    k_bscan<<<1, NBUCK, 0, stream>>>(ghist, bktB, gcur, rowptr, ni, E);
    k_split<<<nchunk, B, 0, stream>>>(src, dst, gcur, part, E);
    k_build<<<nbU, B, 0, stream>>>(part, bktB, rowptr, dinv, col, ni);

    // graph boundaries
    k_start<<<(G + 1 + B - 1) / B, B, 0, stream>>>(batch, startA, ni, G);

    // layer 1
    k_xs<<<(2 * ni + B - 1) / B, B, 0, stream>>>(x, dinv, xs, 2 * ni);
    k_gather1<<<(ni + B - 1) / B, B, 0, stream>>>(rowptr, col, xs, dinv, agg2, ni);
    k_dense2w<<<(int)((n * 8 + B - 1) / B), B, 0, stream>>>(agg2, W1, b1, dinv, hA, ni);

    // layers 2/3 fused, ping-pong hA -> hB -> hA
    const int nblk = (ni + DT32 - 1) / DT32;
    k_layer64<<<nblk, B, 0, stream>>>(rowptr, col, hA, dinv, W2, b2, dinv, hB, ni);
    k_layer64<<<nblk, B, 0, stream>>>(rowptr, col, hB, dinv, W3, b3, nullptr, hA, ni);

    // pool + BN + head
    k_pool_seg<<<(G + 3) / 4, B, 0, stream>>>(hA, startA, pooled, G);
    k_bnstats<<<HDIM, B, 0, stream>>>(pooled, gamma, beta, scale, shift, G);
    k_head<<<(G + B - 1) / B, B, 0, stream>>>(pooled, scale, shift,
                                              fcW1, fcb1, fcW2, fcb2, (float*)d_out, G);
}